// Round 5
// baseline (1070.217 us; speedup 1.0000x reference)
//
#include <hip/hip_runtime.h>
#include <hip/hip_bf16.h>

typedef __attribute__((ext_vector_type(8))) short short8;
typedef __attribute__((ext_vector_type(4))) float f32x4;
typedef __hip_bfloat16 bf16;

#define GLDS16(gp, lp) __builtin_amdgcn_global_load_lds( \
    (const __attribute__((address_space(1))) void*)(gp), \
    (__attribute__((address_space(3))) void*)(lp), 16, 0, 0)

__device__ __forceinline__ short f2bf(float f){
  bf16 h = __float2bfloat16(f);
  return *reinterpret_cast<short*>(&h);
}

// ---- weight convert + transpose: W [K][N] f32  ->  Wt [N][K] bf16 ----
__global__ __launch_bounds__(256) void wconv_kernel(
    const float* __restrict__ W, bf16* __restrict__ Wt, int K, int N)
{
  __shared__ float tile[32][33];
  const int tk = blockIdx.y * 32, tn = blockIdx.x * 32;
  const int t = threadIdx.x;
#pragma unroll
  for (int i = 0; i < 4; ++i){
    int idx = i*256 + t, r = idx >> 5, c = idx & 31;
    tile[r][c] = W[(size_t)(tk + r) * N + (tn + c)];
  }
  __syncthreads();
#pragma unroll
  for (int i = 0; i < 4; ++i){
    int idx = i*256 + t, r = idx >> 5, c = idx & 31;
    Wt[(size_t)(tn + r) * K + (tk + c)] = __float2bfloat16(tile[c][r]);
  }
}

// ---- LayerNorm: x [4096][3072] f32 -> out bf16 ----
__global__ __launch_bounds__(256) void ln_kernel(
    const float* __restrict__ x, const float* __restrict__ g,
    const float* __restrict__ bb, bf16* __restrict__ out)
{
  const int row = blockIdx.x, t = threadIdx.x;
  const float4* xr = (const float4*)(x + (size_t)row * 3072);
  float4 v[3];
  float s = 0.f, s2 = 0.f;
#pragma unroll
  for (int i = 0; i < 3; ++i){
    v[i] = xr[i*256 + t];
    s  += v[i].x + v[i].y + v[i].z + v[i].w;
    s2 += v[i].x*v[i].x + v[i].y*v[i].y + v[i].z*v[i].z + v[i].w*v[i].w;
  }
#pragma unroll
  for (int d = 1; d < 64; d <<= 1){ s += __shfl_xor(s, d); s2 += __shfl_xor(s2, d); }
  __shared__ float red[2][4];
  const int w = t >> 6, lane = t & 63;
  if (lane == 0){ red[0][w] = s; red[1][w] = s2; }
  __syncthreads();
  s  = red[0][0] + red[0][1] + red[0][2] + red[0][3];
  s2 = red[1][0] + red[1][1] + red[1][2] + red[1][3];
  const float mu = s * (1.f/3072.f);
  const float rstd = rsqrtf(s2 * (1.f/3072.f) - mu*mu + 1e-5f);
  const float4* g4 = (const float4*)g;
  const float4* b4 = (const float4*)bb;
  uint2* ov = (uint2*)(out + (size_t)row * 3072);
#pragma unroll
  for (int i = 0; i < 3; ++i){
    const int c = i*256 + t;
    float4 gv = g4[c], bv = b4[c], xv = v[i];
    float o0 = (xv.x - mu) * rstd * gv.x + bv.x;
    float o1 = (xv.y - mu) * rstd * gv.y + bv.y;
    float o2 = (xv.z - mu) * rstd * gv.z + bv.z;
    float o3 = (xv.w - mu) * rstd * gv.w + bv.w;
    uint2 pk;
    pk.x = (unsigned)(unsigned short)f2bf(o0) | ((unsigned)(unsigned short)f2bf(o1) << 16);
    pk.y = (unsigned)(unsigned short)f2bf(o2) | ((unsigned)(unsigned short)f2bf(o3) << 16);
    ov[c] = pk;
  }
}

// ---- 256x256 8-phase GEMM with phase-ahead ds_reads ----
// 512 thr = 8 waves (2M x 4N), BK=64 -> 4 quadrant phases/tile, 16 MFMA each.
// LDS: 2 buffers x 4 slots(Ak0,Bk0,Ak1,Bk1) x 16KB = 128KB.
// Phase q issues ds_reads for q+1 (ping-pong regs), stages 1 half-tile of
// tile t+1, barrier, counted lgkmcnt(just_issued)+sched_barrier, MFMA on
// prev phase's regs. vmcnt(2) BEFORE trailing barrier of q0/q2 (per-wave
// counter must precede a barrier that precedes the dependent cross-wave read).
template<int EPI>
__global__ __launch_bounds__(512, 2) void gemm8_kernel(
    const bf16* __restrict__ A, const bf16* __restrict__ Bt,
    const float* __restrict__ bias, const float* __restrict__ res,
    void* __restrict__ outp, int M, int N, int K)
{
  __shared__ __align__(16) char lds[131072];
  const int NT = K >> 6;
  const int nbx = N >> 8;
  const int nwg = nbx * (M >> 8);
  const int cpx = nwg >> 3;                       // grids are %8==0
  const int bid = blockIdx.x;
  const int lg = (bid & 7) * cpx + (bid >> 3);    // XCD-aware swizzle (bijective)
  const int by = lg / nbx, bx = lg - by * nbx;
  const int m0 = by << 8, n0 = bx << 8;

  const int tid = threadIdx.x;
  const int lane = tid & 63, wid = tid >> 6;
  const int wm = wid >> 2, wn = wid & 3;
  const int l15 = lane & 15, lhi = lane >> 4;

  // staging: half-tile = 256 rows x 32 K-elems (64B rows), linear dest tid*16
  const int row0 = tid >> 2;
  const int ce = ((tid & 3) ^ ((tid >> 3) & 3)) * 8;   // pre-swizzled col elems
  const bf16* pA0 = A  + (size_t)(m0 + row0) * K + ce;
  const bf16* pA1 = pA0 + (size_t)128 * K;
  const bf16* pB0 = Bt + (size_t)(n0 + row0) * K + ce;
  const bf16* pB1 = pB0 + (size_t)128 * K;

  auto stage = [&](int s){
    if (s < (NT << 2)){
      const int kt = s >> 2, idx = s & 3;          // idx: 0=Ak0 1=Bk0 2=Ak1 3=Bk1
      const int koff = (kt << 6) + ((idx >> 1) << 5);
      const bf16* g0 = (idx & 1) ? pB0 : pA0;
      const bf16* g1 = (idx & 1) ? pB1 : pA1;
      char* d = lds + ((kt & 1) << 16) + (idx << 14) + (tid << 4);
      GLDS16(g0 + koff, d);
      GLDS16(g1 + koff, d + 8192);
    }
  };

  f32x4 acc[8][4];
#pragma unroll
  for (int i = 0; i < 8; ++i)
#pragma unroll
    for (int j = 0; j < 4; ++j) acc[i][j] = (f32x4){0.f,0.f,0.f,0.f};

  // fragment read offsets (swizzle per-lane constant: row bits 1-2 from l15)
  const int swz = (lhi ^ ((l15 >> 1) & 3)) << 4;
  const int aoff = (wm*128 + l15)*64 + swz;        // + hi*4096 + i*1024 + ks<<15 + buf<<16
  const int boff = 16384 + (wn*64 + l15)*64 + swz; // + i*1024 + ks<<15 + buf<<16

  short8 A0[4], A1[4], B0[4], B1[4];
  auto dsrA = [&](short8* dst, int buf, int ks, int hi){
#pragma unroll
    for (int i = 0; i < 4; ++i)
      dst[i] = *(const short8*)(lds + (buf << 16) + (ks << 15) + aoff + hi*4096 + i*1024);
  };
  auto dsrB = [&](short8* dst, int buf, int ks){
#pragma unroll
    for (int i = 0; i < 4; ++i)
      dst[i] = *(const short8*)(lds + (buf << 16) + (ks << 15) + boff + i*1024);
  };
  auto mf16 = [&](const short8* Ar, const short8* Br, int r0){
#pragma unroll
    for (int mi = 0; mi < 4; ++mi)
#pragma unroll
      for (int ni = 0; ni < 4; ++ni)
        acc[r0 + mi][ni] = __builtin_amdgcn_mfma_f32_16x16x32_bf16(Ar[mi], Br[ni], acc[r0 + mi][ni], 0,0,0);
  };

  // ---- prologue: stage tile 0; wait slots 0,1; pre-read q0 frags ----
  stage(0); stage(1); stage(2); stage(3);
  asm volatile("s_waitcnt vmcnt(4)" ::: "memory");
  __builtin_amdgcn_s_barrier();
  dsrA(A0, 0, 0, 0);
  dsrB(B0, 0, 0);

  for (int t = 0; t < NT; ++t){
    const int buf = t & 1, nbuf = buf ^ 1;

    // ---- q0: issue A1<-(buf,ks0,hi); MFMA A0 x B0 -> acc[0..3] ----
    dsrA(A1, buf, 0, 1);
    stage((t << 2) + 4);
    __builtin_amdgcn_s_barrier();
    asm volatile("s_waitcnt lgkmcnt(4)" ::: "memory");
    __builtin_amdgcn_sched_barrier(0);
    __builtin_amdgcn_s_setprio(1);
    mf16(A0, B0, 0);
    __builtin_amdgcn_s_setprio(0);
    asm volatile("s_waitcnt vmcnt(2)" ::: "memory");   // (t,2),(t,3) landed, all waves
    __builtin_amdgcn_s_barrier();

    // ---- q1: issue A0<-(buf,ks1,lo), B1<-(buf,ks1); MFMA A1 x B0 -> acc[4..7] ----
    dsrA(A0, buf, 1, 0);
    dsrB(B1, buf, 1);
    stage((t << 2) + 5);
    __builtin_amdgcn_s_barrier();
    asm volatile("s_waitcnt lgkmcnt(8)" ::: "memory");
    __builtin_amdgcn_sched_barrier(0);
    __builtin_amdgcn_s_setprio(1);
    mf16(A1, B0, 4);
    __builtin_amdgcn_s_setprio(0);
    __builtin_amdgcn_s_barrier();

    // ---- q2: issue A1<-(buf,ks1,hi); MFMA A0 x B1 -> acc[0..3] ----
    dsrA(A1, buf, 1, 1);
    stage((t << 2) + 6);
    __builtin_amdgcn_s_barrier();
    asm volatile("s_waitcnt lgkmcnt(4)" ::: "memory");
    __builtin_amdgcn_sched_barrier(0);
    __builtin_amdgcn_s_setprio(1);
    mf16(A0, B1, 0);
    __builtin_amdgcn_s_setprio(0);
    asm volatile("s_waitcnt vmcnt(2)" ::: "memory");   // (t+1,0),(t+1,1) landed, all waves
    __builtin_amdgcn_s_barrier();

    // ---- q3: issue A0<-(nbuf,ks0,lo), B0<-(nbuf,ks0) [tile t+1]; MFMA A1 x B1 -> acc[4..7] ----
    dsrA(A0, nbuf, 0, 0);
    dsrB(B0, nbuf, 0);
    stage((t << 2) + 7);
    __builtin_amdgcn_s_barrier();
    asm volatile("s_waitcnt lgkmcnt(8)" ::: "memory");
    __builtin_amdgcn_sched_barrier(0);
    __builtin_amdgcn_s_setprio(1);
    mf16(A1, B1, 4);
    __builtin_amdgcn_s_setprio(0);
    __builtin_amdgcn_s_barrier();
  }

  // ---- epilogue ----
  const int rb = m0 + wm*128 + (lhi << 2);
  const int cb0 = n0 + wn*64 + l15;
#pragma unroll
  for (int mi = 0; mi < 8; ++mi){
#pragma unroll
    for (int ni = 0; ni < 4; ++ni){
      const int col = cb0 + ni*16;
#pragma unroll
      for (int r = 0; r < 4; ++r){
        const int row = rb + mi*16 + r;
        float vv = acc[mi][ni][r];
        if constexpr (EPI == 0){
          const int cbuf = col / 3072;
          const int cl = col - cbuf*3072;
          ((bf16*)outp)[(size_t)cbuf*M*3072 + (size_t)row*3072 + cl] = __float2bfloat16(vv);
        } else if constexpr (EPI == 1){
          ((float*)outp)[(size_t)row*N + col] = vv + bias[col] + res[(size_t)row*N + col];
        } else {
          float xx = vv + bias[col];
          float y = 0.7978845608f*(xx + 0.044715f*xx*xx*xx);
          float e = exp2f(fminf(y, 15.f) * 2.885390082f);   // e^{2y}
          ((bf16*)outp)[(size_t)row*N + col] = __float2bfloat16(xx * e / (e + 1.f));
        }
      }
    }
  }
}

// ---- V transpose: vb [B*S][H] -> VT [B][NH][96][1024] ----
__global__ __launch_bounds__(256) void vt_kernel(
    const bf16* __restrict__ V, bf16* __restrict__ VT)
{
  const int bh = blockIdx.x, st = blockIdx.y;
  const int b = bh >> 5, h = bh & 31;
  const int t = threadIdx.x;
  __shared__ __align__(16) short tile[96][72];
  const int s0 = st*64;
  const short* src = (const short*)V + (size_t)(b*1024 + s0)*3072 + h*96;
#pragma unroll
  for (int i = 0; i < 3; ++i){
    int c = t + i*256;
    int s = c/12, dc = c - s*12;
    short8 v8 = *(const short8*)(src + (size_t)s*3072 + dc*8);
#pragma unroll
    for (int e = 0; e < 8; ++e) tile[dc*8+e][s] = v8[e];
  }
  __syncthreads();
  short* dst = (short*)VT + ((size_t)bh*96)*1024 + s0;
#pragma unroll
  for (int i = 0; i < 3; ++i){
    int c = t + i*256;
    int d = c >> 3, kc = c & 7;
    short8 v8 = *(const short8*)(&tile[0][0] + d*72 + kc*8);
    *(short8*)(dst + (size_t)d*1024 + kc*8) = v8;
  }
}

// ---- causal flash attention, D=96, S=1024, bf16 ----
__global__ __launch_bounds__(256, 4) void attn_kernel(
    const bf16* __restrict__ Q, const bf16* __restrict__ Kg,
    const bf16* __restrict__ VT, bf16* __restrict__ O)
{
  const int bh = blockIdx.x;
  const int yp = blockIdx.y;
  const int b = bh >> 5, h = bh & 31;
  const int t = threadIdx.x;
  const int lane = t & 63, w = t >> 6;
  const size_t RS = 3072;
  const size_t base = (size_t)(b * 1024) * RS + (size_t)h * 96;
  const short* VTh = (const short*)VT + (size_t)bh * 96 * 1024;

  __shared__ __align__(16) bf16 Ks[64*128];
  __shared__ __align__(16) bf16 Vt[96*64];
  __shared__ __align__(16) bf16 Ps[4][16][72];

  char* KsB = (char*)Ks;
  char* VtB = (char*)Vt;
  const short* PsW = (const short*)&Ps[w][0][0];
  const float sc = 0.1020620726f * 1.44269504089f;
  const int l15 = lane & 15, lhi = lane >> 4;

#pragma unroll
  for (int sel = 0; sel < 2; ++sel){
    const int qt = sel ? (15 - yp) : yp;
    const int q0 = qt*64 + w*16;

    short8 aq[3];
    {
      const short* qp = (const short*)Q + base + (size_t)(q0 + l15) * RS + (lhi << 3);
#pragma unroll
      for (int ks = 0; ks < 3; ++ks) aq[ks] = *(const short8*)(qp + ks*32);
    }
    f32x4 acc[6];
#pragma unroll
    for (int i = 0; i < 6; ++i) acc[i] = (f32x4){0.f,0.f,0.f,0.f};
    float mrow[4] = {-3e38f,-3e38f,-3e38f,-3e38f};
    float lrow[4] = {0.f,0.f,0.f,0.f};

    for (int kt = 0; kt <= qt; ++kt){
      const int kv0 = kt*64;
      __syncthreads();
      {
        short8 kr[4], vr[3];
#pragma unroll
        for (int i = 0; i < 4; ++i){
          int c = t + i*256, kv = c >> 4, dc = c & 15;
          kr[i] = *(const short8*)((const short*)Kg + base + (size_t)(kv0 + kv)*RS + dc*8);
        }
#pragma unroll
        for (int i = 0; i < 3; ++i){
          int c = t + i*256, d = c >> 3, kvc = c & 7;
          vr[i] = *(const short8*)(VTh + (size_t)d*1024 + kv0 + kvc*8);
        }
#pragma unroll
        for (int i = 0; i < 4; ++i){
          int c = t + i*256, kv = c >> 4, dc = c & 15;
          *(short8*)(KsB + kv*256 + ((dc ^ (kv & 7)) << 4)) = kr[i];
        }
#pragma unroll
        for (int i = 0; i < 3; ++i){
          int c = t + i*256, d = c >> 3, kvc = c & 7;
          *(short8*)(VtB + d*128 + ((kvc ^ (d & 7)) << 4)) = vr[i];
        }
      }
      __syncthreads();

      float sv[4][4];
      const bool diag = (kt == qt);
#pragma unroll
      for (int ct = 0; ct < 4; ++ct){
        const int kvl = ct*16 + l15;
        f32x4 s4 = (f32x4){0.f,0.f,0.f,0.f};
#pragma unroll
        for (int ks = 0; ks < 3; ++ks){
          short8 bk = *(const short8*)(KsB + kvl*256 + (((ks*4 + lhi) ^ (kvl & 7)) << 4));
          s4 = __builtin_amdgcn_mfma_f32_16x16x32_bf16(aq[ks], bk, s4, 0,0,0);
        }
#pragma unroll
        for (int r = 0; r < 4; ++r){
          float vvl = s4[r] * sc;
          if (diag){
            int kvg = kv0 + kvl;
            int qg  = q0 + (lhi << 2) + r;
            if (kvg > qg) vvl = -3e38f;
          }
          sv[ct][r] = vvl;
        }
      }

      float alpha[4];
#pragma unroll
      for (int r = 0; r < 4; ++r){
        float m = fmaxf(fmaxf(sv[0][r], sv[1][r]), fmaxf(sv[2][r], sv[3][r]));
#pragma unroll
        for (int dd = 1; dd < 16; dd <<= 1) m = fmaxf(m, __shfl_xor(m, dd));
        float mn = fmaxf(mrow[r], m);
        alpha[r] = exp2f(mrow[r] - mn);
        mrow[r] = mn;
        float rs = 0.f;
#pragma unroll
        for (int ct = 0; ct < 4; ++ct){
          float p = exp2f(sv[ct][r] - mn);
          sv[ct][r] = p;
          rs += p;
        }
#pragma unroll
        for (int dd = 1; dd < 16; dd <<= 1) rs += __shfl_xor(rs, dd);
        lrow[r] = lrow[r]*alpha[r] + rs;
      }
#pragma unroll
      for (int i = 0; i < 6; ++i)
#pragma unroll
        for (int r = 0; r < 4; ++r) acc[i][r] *= alpha[r];

#pragma unroll
      for (int ct = 0; ct < 4; ++ct)
#pragma unroll
        for (int r = 0; r < 4; ++r)
          Ps[w][(lhi << 2) + r][ct*16 + l15] = __float2bfloat16(sv[ct][r]);

#pragma unroll
      for (int ks2 = 0; ks2 < 2; ++ks2){
        short8 pa = *(const short8*)(PsW + l15*72 + ks2*32 + (lhi << 3));
#pragma unroll
        for (int dt = 0; dt < 6; ++dt){
          const int dl = dt*16 + l15;
          short8 vbf = *(const short8*)(VtB + dl*128 + (((ks2*4 + lhi) ^ (dl & 7)) << 4));
          acc[dt] = __builtin_amdgcn_mfma_f32_16x16x32_bf16(pa, vbf, acc[dt], 0,0,0);
        }
      }
    }

    bf16* Ob = (bf16*)O + base + (size_t)q0 * RS;
#pragma unroll
    for (int dt = 0; dt < 6; ++dt){
#pragma unroll
      for (int r = 0; r < 4; ++r){
        float vvl = acc[dt][r] / lrow[r];
        Ob[(size_t)((lhi << 2) + r) * RS + dt*16 + l15] = __float2bfloat16(vvl);
      }
    }
  }
}

extern "C" void kernel_launch(void* const* d_in, const int* in_sizes, int n_in,
                              void* d_out, int out_size, void* d_ws, size_t ws_size,
                              hipStream_t stream)
{
  (void)in_sizes; (void)n_in; (void)out_size; (void)ws_size;
  const float* x_in = (const float*)d_in[0];
  const float* Wq   = (const float*)d_in[2];
  const float* Wk   = (const float*)d_in[3];
  const float* Wv   = (const float*)d_in[4];
  const float* Wo   = (const float*)d_in[5];
  const float* bo   = (const float*)d_in[6];
  const float* ln1g = (const float*)d_in[7];
  const float* ln1b = (const float*)d_in[8];
  const float* ln2g = (const float*)d_in[9];
  const float* ln2b = (const float*)d_in[10];
  const float* W1   = (const float*)d_in[11];
  const float* b1   = (const float*)d_in[12];
  const float* W2   = (const float*)d_in[13];
  const float* b2   = (const float*)d_in[14];

  char* ws = (char*)d_ws;
  size_t off = 0;
  auto alloc = [&](size_t bytes) -> char* {
    char* p = ws + off; off += (bytes + 255) & ~(size_t)255; return p;
  };
  const size_t H = 3072, I = 8192, M = 4096;
  bf16* Wqt = (bf16*)alloc(H*H*2);   // Wqt/Wkt/Wvt contiguous -> fused [9216][3072]
  bf16* Wkt = (bf16*)alloc(H*H*2);
  bf16* Wvt = (bf16*)alloc(H*H*2);
  bf16* Wot = (bf16*)alloc(H*H*2);
  bf16* W1t = (bf16*)alloc(H*I*2);
  bf16* W2t = (bf16*)alloc(H*I*2);
  bf16* hb  = (bf16*)alloc(M*H*2);
  bf16* qb  = (bf16*)alloc(M*H*2);   // qb/kb/vb contiguous -> fused QKV output target
  bf16* kb  = (bf16*)alloc(M*H*2);
  bf16* vb  = (bf16*)alloc(M*H*2);
  bf16* ctx = (bf16*)alloc(M*H*2);
  float* x2 = (float*)d_out;
  bf16* h2  = hb;
  bf16* VT  = hb;
  bf16* act = qb;
  (void)kb; (void)vb;

  // 1. weight convert+transpose
  wconv_kernel<<<dim3(96, 96),  256, 0, stream>>>(Wq, Wqt, 3072, 3072);
  wconv_kernel<<<dim3(96, 96),  256, 0, stream>>>(Wk, Wkt, 3072, 3072);
  wconv_kernel<<<dim3(96, 96),  256, 0, stream>>>(Wv, Wvt, 3072, 3072);
  wconv_kernel<<<dim3(96, 96),  256, 0, stream>>>(Wo, Wot, 3072, 3072);
  wconv_kernel<<<dim3(256, 96), 256, 0, stream>>>(W1, W1t, 3072, 8192);
  wconv_kernel<<<dim3(96, 256), 256, 0, stream>>>(W2, W2t, 8192, 3072);

  // 2. LN1
  ln_kernel<<<4096, 256, 0, stream>>>(x_in, ln1g, ln1b, hb);

  // 3. fused QKV projection (N = 9216)
  gemm8_kernel<0><<<576, 512, 0, stream>>>(hb, Wqt, nullptr, nullptr, qb, 4096, 9216, 3072);

  // 3.5 V transpose
  vt_kernel<<<dim3(128, 16), 256, 0, stream>>>(vb, VT);

  // 4. causal attention
  attn_kernel<<<dim3(128, 8), 256, 0, stream>>>(qb, kb, VT, ctx);

  // 5. O projection + bias + residual -> x2 (f32, in d_out)
  gemm8_kernel<1><<<192, 512, 0, stream>>>(ctx, Wot, bo, x_in, x2, 4096, 3072, 3072);

  // 6. LN2
  ln_kernel<<<4096, 256, 0, stream>>>(x2, ln2g, ln2b, h2);

  // 7. MLP up + GELU
  gemm8_kernel<2><<<512, 512, 0, stream>>>(h2, W1t, b1, nullptr, act, 4096, 8192, 3072);

  // 8. MLP down + bias + residual -> out
  gemm8_kernel<1><<<192, 512, 0, stream>>>(act, W2t, b2, x2, (float*)d_out, 4096, 3072, 8192);
}

// Round 6
// 1024.596 us; speedup vs baseline: 1.0445x; 1.0445x over previous
//
#include <hip/hip_runtime.h>
#include <hip/hip_bf16.h>

typedef __attribute__((ext_vector_type(8))) short short8;
typedef __attribute__((ext_vector_type(4))) float f32x4;
typedef __hip_bfloat16 bf16;

#define GLDS16(gp, lp) __builtin_amdgcn_global_load_lds( \
    (const __attribute__((address_space(1))) void*)(gp), \
    (__attribute__((address_space(3))) void*)(lp), 16, 0, 0)

__device__ __forceinline__ short f2bf(float f){
  bf16 h = __float2bfloat16(f);
  return *reinterpret_cast<short*>(&h);
}

// ---- weight convert + transpose: W [K][N] f32  ->  Wt [N][K] bf16 ----
__global__ __launch_bounds__(256) void wconv_kernel(
    const float* __restrict__ W, bf16* __restrict__ Wt, int K, int N)
{
  __shared__ float tile[32][33];
  const int tk = blockIdx.y * 32, tn = blockIdx.x * 32;
  const int t = threadIdx.x;
#pragma unroll
  for (int i = 0; i < 4; ++i){
    int idx = i*256 + t, r = idx >> 5, c = idx & 31;
    tile[r][c] = W[(size_t)(tk + r) * N + (tn + c)];
  }
  __syncthreads();
#pragma unroll
  for (int i = 0; i < 4; ++i){
    int idx = i*256 + t, r = idx >> 5, c = idx & 31;
    Wt[(size_t)(tn + r) * K + (tk + c)] = __float2bfloat16(tile[c][r]);
  }
}

// ---- LayerNorm: x [4096][3072] f32 -> out bf16 ----
__global__ __launch_bounds__(256) void ln_kernel(
    const float* __restrict__ x, const float* __restrict__ g,
    const float* __restrict__ bb, bf16* __restrict__ out)
{
  const int row = blockIdx.x, t = threadIdx.x;
  const float4* xr = (const float4*)(x + (size_t)row * 3072);
  float4 v[3];
  float s = 0.f, s2 = 0.f;
#pragma unroll
  for (int i = 0; i < 3; ++i){
    v[i] = xr[i*256 + t];
    s  += v[i].x + v[i].y + v[i].z + v[i].w;
    s2 += v[i].x*v[i].x + v[i].y*v[i].y + v[i].z*v[i].z + v[i].w*v[i].w;
  }
#pragma unroll
  for (int d = 1; d < 64; d <<= 1){ s += __shfl_xor(s, d); s2 += __shfl_xor(s2, d); }
  __shared__ float red[2][4];
  const int w = t >> 6, lane = t & 63;
  if (lane == 0){ red[0][w] = s; red[1][w] = s2; }
  __syncthreads();
  s  = red[0][0] + red[0][1] + red[0][2] + red[0][3];
  s2 = red[1][0] + red[1][1] + red[1][2] + red[1][3];
  const float mu = s * (1.f/3072.f);
  const float rstd = rsqrtf(s2 * (1.f/3072.f) - mu*mu + 1e-5f);
  const float4* g4 = (const float4*)g;
  const float4* b4 = (const float4*)bb;
  uint2* ov = (uint2*)(out + (size_t)row * 3072);
#pragma unroll
  for (int i = 0; i < 3; ++i){
    const int c = i*256 + t;
    float4 gv = g4[c], bv = b4[c], xv = v[i];
    float o0 = (xv.x - mu) * rstd * gv.x + bv.x;
    float o1 = (xv.y - mu) * rstd * gv.y + bv.y;
    float o2 = (xv.z - mu) * rstd * gv.z + bv.z;
    float o3 = (xv.w - mu) * rstd * gv.w + bv.w;
    uint2 pk;
    pk.x = (unsigned)(unsigned short)f2bf(o0) | ((unsigned)(unsigned short)f2bf(o1) << 16);
    pk.y = (unsigned)(unsigned short)f2bf(o2) | ((unsigned)(unsigned short)f2bf(o3) << 16);
    ov[c] = pk;
  }
}

// ---- 256x256 GEMM, BK=32, 4-buffer ring staged 3 tiles ahead ----
// 512 thr = 8 waves (2M x 4N). LDS: 4 x 32KB buffers (A 16KB + B 16KB).
// Per tile: vmcnt(8) + ONE barrier; q0 {stageA(t+3), read A-lo+B, 16 MFMA},
// q1 {stageB(t+3), read A-hi, 16 MFMA}. Invariant at vmcnt: outstanding
// loads belong to tiles {t,t+1,t+2} (12); vmcnt(8) drains tile t's 4 (~6
// phases of slack, covers HBM latency). Ring safety: window t writes only
// buf (t-1)&3, reads only t&3; reads of (t-1)&3 lgkm-completed pre-barrier.
template<int EPI>
__global__ __launch_bounds__(512, 2) void gemm8_kernel(
    const bf16* __restrict__ A, const bf16* __restrict__ Bt,
    const float* __restrict__ bias, const float* __restrict__ res,
    void* __restrict__ outp, int M, int N, int K)
{
  __shared__ __align__(16) char lds[131072];
  const int NT = K >> 5;                          // BK=32 tiles
  const int nbx = N >> 8;
  const int nwg = nbx * (M >> 8);
  const int cpx = nwg >> 3;                       // grids are %8==0
  const int bid = blockIdx.x;
  const int lg = (bid & 7) * cpx + (bid >> 3);    // XCD-aware swizzle (bijective)
  const int by = lg / nbx, bx = lg - by * nbx;
  const int m0 = by << 8, n0 = bx << 8;

  const int tid = threadIdx.x;
  const int lane = tid & 63, wid = tid >> 6;
  const int wm = wid >> 2, wn = wid & 3;
  const int l15 = lane & 15, lhi = lane >> 4;

  // staging: tile region = 256 rows x 32 K-elems (64B rows), linear dest
  // tid*16 (+8192 for rows 128-255); source col pre-swizzled by ((row>>1)&3)
  const int row0 = tid >> 2;
  const int ce = ((tid & 3) ^ ((tid >> 3) & 3)) * 8;
  const bf16* pA0 = A  + (size_t)(m0 + row0) * K + ce;
  const bf16* pA1 = pA0 + (size_t)128 * K;
  const bf16* pB0 = Bt + (size_t)(n0 + row0) * K + ce;
  const bf16* pB1 = pB0 + (size_t)128 * K;

  auto stageA = [&](int u){
    if (u < NT){
      char* d = lds + ((u & 3) << 15) + (tid << 4);
      GLDS16(pA0 + ((size_t)u << 5), d);
      GLDS16(pA1 + ((size_t)u << 5), d + 8192);
    }
  };
  auto stageB = [&](int u){
    if (u < NT){
      char* d = lds + ((u & 3) << 15) + 16384 + (tid << 4);
      GLDS16(pB0 + ((size_t)u << 5), d);
      GLDS16(pB1 + ((size_t)u << 5), d + 8192);
    }
  };

  f32x4 acc[8][4];
#pragma unroll
  for (int i = 0; i < 8; ++i)
#pragma unroll
    for (int j = 0; j < 4; ++j) acc[i][j] = (f32x4){0.f,0.f,0.f,0.f};

  // fragment read offsets (swizzle per-lane constant: row bits 1-2 from l15)
  const int swz = (lhi ^ ((l15 >> 1) & 3)) << 4;
  const int aoff = (wm*128 + l15)*64 + swz;        // + mi*1024
  const int boff = 16384 + (wn*64 + l15)*64 + swz; // + ni*1024

  stageA(0); stageB(0); stageA(1); stageB(1); stageA(2); stageB(2);

  for (int t = 0; t < NT; ++t){
    const char* Lb = lds + ((t & 3) << 15);
    asm volatile("s_waitcnt vmcnt(8)" ::: "memory");   // tile t fully landed (mine)
    __builtin_amdgcn_s_barrier();                      // ...and everyone's
    __builtin_amdgcn_sched_barrier(0);

    // ---- q0: stage A(t+3); read A-lo + B; MFMA acc[0..3] ----
    stageA(t + 3);
    short8 a[4], b[4];
#pragma unroll
    for (int i = 0; i < 4; ++i) a[i] = *(const short8*)(Lb + aoff + i*1024);
#pragma unroll
    for (int i = 0; i < 4; ++i) b[i] = *(const short8*)(Lb + boff + i*1024);
    __builtin_amdgcn_s_setprio(1);
#pragma unroll
    for (int mi = 0; mi < 4; ++mi)
#pragma unroll
      for (int ni = 0; ni < 4; ++ni)
        acc[mi][ni] = __builtin_amdgcn_mfma_f32_16x16x32_bf16(a[mi], b[ni], acc[mi][ni], 0,0,0);
    __builtin_amdgcn_s_setprio(0);

    // ---- q1: stage B(t+3); read A-hi; MFMA acc[4..7] ----
    stageB(t + 3);
#pragma unroll
    for (int i = 0; i < 4; ++i) a[i] = *(const short8*)(Lb + aoff + (4+i)*1024);
    __builtin_amdgcn_s_setprio(1);
#pragma unroll
    for (int mi = 0; mi < 4; ++mi)
#pragma unroll
      for (int ni = 0; ni < 4; ++ni)
        acc[4+mi][ni] = __builtin_amdgcn_mfma_f32_16x16x32_bf16(a[mi], b[ni], acc[4+mi][ni], 0,0,0);
    __builtin_amdgcn_s_setprio(0);
  }

  // ---- epilogue ----
  const int rb = m0 + wm*128 + (lhi << 2);
  const int cb0 = n0 + wn*64 + l15;
#pragma unroll
  for (int mi = 0; mi < 8; ++mi){
#pragma unroll
    for (int ni = 0; ni < 4; ++ni){
      const int col = cb0 + ni*16;
#pragma unroll
      for (int r = 0; r < 4; ++r){
        const int row = rb + mi*16 + r;
        float vv = acc[mi][ni][r];
        if constexpr (EPI == 0){
          const int cbuf = col / 3072;
          const int cl = col - cbuf*3072;
          ((bf16*)outp)[(size_t)cbuf*M*3072 + (size_t)row*3072 + cl] = __float2bfloat16(vv);
        } else if constexpr (EPI == 1){
          ((float*)outp)[(size_t)row*N + col] = vv + bias[col] + res[(size_t)row*N + col];
        } else {
          float xx = vv + bias[col];
          float y = 0.7978845608f*(xx + 0.044715f*xx*xx*xx);
          float e = exp2f(fminf(y, 15.f) * 2.885390082f);   // e^{2y}
          ((bf16*)outp)[(size_t)row*N + col] = __float2bfloat16(xx * e / (e + 1.f));
        }
      }
    }
  }
}

// ---- V transpose: vb [B*S][H] -> VT [B][NH][96][1024] ----
__global__ __launch_bounds__(256) void vt_kernel(
    const bf16* __restrict__ V, bf16* __restrict__ VT)
{
  const int bh = blockIdx.x, st = blockIdx.y;
  const int b = bh >> 5, h = bh & 31;
  const int t = threadIdx.x;
  __shared__ __align__(16) short tile[96][72];
  const int s0 = st*64;
  const short* src = (const short*)V + (size_t)(b*1024 + s0)*3072 + h*96;
#pragma unroll
  for (int i = 0; i < 3; ++i){
    int c = t + i*256;
    int s = c/12, dc = c - s*12;
    short8 v8 = *(const short8*)(src + (size_t)s*3072 + dc*8);
#pragma unroll
    for (int e = 0; e < 8; ++e) tile[dc*8+e][s] = v8[e];
  }
  __syncthreads();
  short* dst = (short*)VT + ((size_t)bh*96)*1024 + s0;
#pragma unroll
  for (int i = 0; i < 3; ++i){
    int c = t + i*256;
    int d = c >> 3, kc = c & 7;
    short8 v8 = *(const short8*)(&tile[0][0] + d*72 + kc*8);
    *(short8*)(dst + (size_t)d*1024 + kc*8) = v8;
  }
}

// ---- causal flash attention, D=96, S=1024, bf16 ----
__global__ __launch_bounds__(256, 4) void attn_kernel(
    const bf16* __restrict__ Q, const bf16* __restrict__ Kg,
    const bf16* __restrict__ VT, bf16* __restrict__ O)
{
  const int bh = blockIdx.x;
  const int yp = blockIdx.y;
  const int b = bh >> 5, h = bh & 31;
  const int t = threadIdx.x;
  const int lane = t & 63, w = t >> 6;
  const size_t RS = 3072;
  const size_t base = (size_t)(b * 1024) * RS + (size_t)h * 96;
  const short* VTh = (const short*)VT + (size_t)bh * 96 * 1024;

  __shared__ __align__(16) bf16 Ks[64*128];
  __shared__ __align__(16) bf16 Vt[96*64];
  __shared__ __align__(16) bf16 Ps[4][16][72];

  char* KsB = (char*)Ks;
  char* VtB = (char*)Vt;
  const short* PsW = (const short*)&Ps[w][0][0];
  const float sc = 0.1020620726f * 1.44269504089f;
  const int l15 = lane & 15, lhi = lane >> 4;

#pragma unroll
  for (int sel = 0; sel < 2; ++sel){
    const int qt = sel ? (15 - yp) : yp;
    const int q0 = qt*64 + w*16;

    short8 aq[3];
    {
      const short* qp = (const short*)Q + base + (size_t)(q0 + l15) * RS + (lhi << 3);
#pragma unroll
      for (int ks = 0; ks < 3; ++ks) aq[ks] = *(const short8*)(qp + ks*32);
    }
    f32x4 acc[6];
#pragma unroll
    for (int i = 0; i < 6; ++i) acc[i] = (f32x4){0.f,0.f,0.f,0.f};
    float mrow[4] = {-3e38f,-3e38f,-3e38f,-3e38f};
    float lrow[4] = {0.f,0.f,0.f,0.f};

    for (int kt = 0; kt <= qt; ++kt){
      const int kv0 = kt*64;
      __syncthreads();
      {
        short8 kr[4], vr[3];
#pragma unroll
        for (int i = 0; i < 4; ++i){
          int c = t + i*256, kv = c >> 4, dc = c & 15;
          kr[i] = *(const short8*)((const short*)Kg + base + (size_t)(kv0 + kv)*RS + dc*8);
        }
#pragma unroll
        for (int i = 0; i < 3; ++i){
          int c = t + i*256, d = c >> 3, kvc = c & 7;
          vr[i] = *(const short8*)(VTh + (size_t)d*1024 + kv0 + kvc*8);
        }
#pragma unroll
        for (int i = 0; i < 4; ++i){
          int c = t + i*256, kv = c >> 4, dc = c & 15;
          *(short8*)(KsB + kv*256 + ((dc ^ (kv & 7)) << 4)) = kr[i];
        }
#pragma unroll
        for (int i = 0; i < 3; ++i){
          int c = t + i*256, d = c >> 3, kvc = c & 7;
          *(short8*)(VtB + d*128 + ((kvc ^ (d & 7)) << 4)) = vr[i];
        }
      }
      __syncthreads();

      float sv[4][4];
      const bool diag = (kt == qt);
#pragma unroll
      for (int ct = 0; ct < 4; ++ct){
        const int kvl = ct*16 + l15;
        f32x4 s4 = (f32x4){0.f,0.f,0.f,0.f};
#pragma unroll
        for (int ks = 0; ks < 3; ++ks){
          short8 bk = *(const short8*)(KsB + kvl*256 + (((ks*4 + lhi) ^ (kvl & 7)) << 4));
          s4 = __builtin_amdgcn_mfma_f32_16x16x32_bf16(aq[ks], bk, s4, 0,0,0);
        }
#pragma unroll
        for (int r = 0; r < 4; ++r){
          float vvl = s4[r] * sc;
          if (diag){
            int kvg = kv0 + kvl;
            int qg  = q0 + (lhi << 2) + r;
            if (kvg > qg) vvl = -3e38f;
          }
          sv[ct][r] = vvl;
        }
      }

      float alpha[4];
#pragma unroll
      for (int r = 0; r < 4; ++r){
        float m = fmaxf(fmaxf(sv[0][r], sv[1][r]), fmaxf(sv[2][r], sv[3][r]));
#pragma unroll
        for (int dd = 1; dd < 16; dd <<= 1) m = fmaxf(m, __shfl_xor(m, dd));
        float mn = fmaxf(mrow[r], m);
        alpha[r] = exp2f(mrow[r] - mn);
        mrow[r] = mn;
        float rs = 0.f;
#pragma unroll
        for (int ct = 0; ct < 4; ++ct){
          float p = exp2f(sv[ct][r] - mn);
          sv[ct][r] = p;
          rs += p;
        }
#pragma unroll
        for (int dd = 1; dd < 16; dd <<= 1) rs += __shfl_xor(rs, dd);
        lrow[r] = lrow[r]*alpha[r] + rs;
      }
#pragma unroll
      for (int i = 0; i < 6; ++i)
#pragma unroll
        for (int r = 0; r < 4; ++r) acc[i][r] *= alpha[r];

#pragma unroll
      for (int ct = 0; ct < 4; ++ct)
#pragma unroll
        for (int r = 0; r < 4; ++r)
          Ps[w][(lhi << 2) + r][ct*16 + l15] = __float2bfloat16(sv[ct][r]);

#pragma unroll
      for (int ks2 = 0; ks2 < 2; ++ks2){
        short8 pa = *(const short8*)(PsW + l15*72 + ks2*32 + (lhi << 3));
#pragma unroll
        for (int dt = 0; dt < 6; ++dt){
          const int dl = dt*16 + l15;
          short8 vbf = *(const short8*)(VtB + dl*128 + (((ks2*4 + lhi) ^ (dl & 7)) << 4));
          acc[dt] = __builtin_amdgcn_mfma_f32_16x16x32_bf16(pa, vbf, acc[dt], 0,0,0);
        }
      }
    }

    bf16* Ob = (bf16*)O + base + (size_t)q0 * RS;
#pragma unroll
    for (int dt = 0; dt < 6; ++dt){
#pragma unroll
      for (int r = 0; r < 4; ++r){
        float vvl = acc[dt][r] / lrow[r];
        Ob[(size_t)((lhi << 2) + r) * RS + dt*16 + l15] = __float2bfloat16(vvl);
      }
    }
  }
}

extern "C" void kernel_launch(void* const* d_in, const int* in_sizes, int n_in,
                              void* d_out, int out_size, void* d_ws, size_t ws_size,
                              hipStream_t stream)
{
  (void)in_sizes; (void)n_in; (void)out_size; (void)ws_size;
  const float* x_in = (const float*)d_in[0];
  const float* Wq   = (const float*)d_in[2];
  const float* Wk   = (const float*)d_in[3];
  const float* Wv   = (const float*)d_in[4];
  const float* Wo   = (const float*)d_in[5];
  const float* bo   = (const float*)d_in[6];
  const float* ln1g = (const float*)d_in[7];
  const float* ln1b = (const float*)d_in[8];
  const float* ln2g = (const float*)d_in[9];
  const float* ln2b = (const float*)d_in[10];
  const float* W1   = (const float*)d_in[11];
  const float* b1   = (const float*)d_in[12];
  const float* W2   = (const float*)d_in[13];
  const float* b2   = (const float*)d_in[14];

  char* ws = (char*)d_ws;
  size_t off = 0;
  auto alloc = [&](size_t bytes) -> char* {
    char* p = ws + off; off += (bytes + 255) & ~(size_t)255; return p;
  };
  const size_t H = 3072, I = 8192, M = 4096;
  bf16* Wqt = (bf16*)alloc(H*H*2);   // Wqt/Wkt/Wvt contiguous -> fused [9216][3072]
  bf16* Wkt = (bf16*)alloc(H*H*2);
  bf16* Wvt = (bf16*)alloc(H*H*2);
  bf16* Wot = (bf16*)alloc(H*H*2);
  bf16* W1t = (bf16*)alloc(H*I*2);
  bf16* W2t = (bf16*)alloc(H*I*2);
  bf16* hb  = (bf16*)alloc(M*H*2);
  bf16* qb  = (bf16*)alloc(M*H*2);   // qb/kb/vb contiguous -> fused QKV output target
  bf16* kb  = (bf16*)alloc(M*H*2);
  bf16* vb  = (bf16*)alloc(M*H*2);
  bf16* ctx = (bf16*)alloc(M*H*2);
  float* x2 = (float*)d_out;
  bf16* h2  = hb;
  bf16* VT  = hb;
  bf16* act = qb;
  (void)kb; (void)vb;

  // 1. weight convert+transpose
  wconv_kernel<<<dim3(96, 96),  256, 0, stream>>>(Wq, Wqt, 3072, 3072);
  wconv_kernel<<<dim3(96, 96),  256, 0, stream>>>(Wk, Wkt, 3072, 3072);
  wconv_kernel<<<dim3(96, 96),  256, 0, stream>>>(Wv, Wvt, 3072, 3072);
  wconv_kernel<<<dim3(96, 96),  256, 0, stream>>>(Wo, Wot, 3072, 3072);
  wconv_kernel<<<dim3(256, 96), 256, 0, stream>>>(W1, W1t, 3072, 8192);
  wconv_kernel<<<dim3(96, 256), 256, 0, stream>>>(W2, W2t, 8192, 3072);

  // 2. LN1
  ln_kernel<<<4096, 256, 0, stream>>>(x_in, ln1g, ln1b, hb);

  // 3. fused QKV projection (N = 9216)
  gemm8_kernel<0><<<576, 512, 0, stream>>>(hb, Wqt, nullptr, nullptr, qb, 4096, 9216, 3072);

  // 3.5 V transpose
  vt_kernel<<<dim3(128, 16), 256, 0, stream>>>(vb, VT);

  // 4. causal attention
  attn_kernel<<<dim3(128, 8), 256, 0, stream>>>(qb, kb, VT, ctx);

  // 5. O projection + bias + residual -> x2 (f32, in d_out)
  gemm8_kernel<1><<<192, 512, 0, stream>>>(ctx, Wot, bo, x_in, x2, 4096, 3072, 3072);

  // 6. LN2
  ln_kernel<<<4096, 256, 0, stream>>>(x2, ln2g, ln2b, h2);

  // 7. MLP up + GELU
  gemm8_kernel<2><<<512, 512, 0, stream>>>(h2, W1t, b1, nullptr, act, 4096, 8192, 3072);

  // 8. MLP down + bias + residual -> out
  gemm8_kernel<1><<<192, 512, 0, stream>>>(act, W2t, b2, x2, (float*)d_out, 4096, 3072, 8192);
}